// Round 8
// baseline (195.230 us; speedup 1.0000x reference)
//
#include <hip/hip_runtime.h>

#define NN 10000
#define NE 160000
#define KD 1433
#define KP 1536    // padded K (zero-filled in Wb)
#define SK1 2      // split-K factor for mm1 (partial buffers, no atomics)
#define KC 768     // per-block K chunk = KP/SK1
#define KSTEP 64   // K per LDS stage
#define NSTG 12    // KC/KSTEP

typedef unsigned short u16;
typedef __attribute__((ext_vector_type(4))) float f32x4;
typedef __attribute__((ext_vector_type(8))) short bf16x8;
typedef __attribute__((ext_vector_type(4), aligned(4))) float f32x4u;

__device__ __forceinline__ u16 f2bf(float f) {
    union { float f; unsigned u; } v; v.f = f;
    unsigned r = (v.u + 0x7FFF + ((v.u >> 16) & 1)) >> 16;
    return (u16)r;
}

// ---------- edge dtype detect ----------
__global__ __launch_bounds__(256) void detect_kernel(const int* __restrict__ e, int* __restrict__ flag) {
    __shared__ int nz;
    if (threadIdx.x == 0) nz = 0;
    __syncthreads();
    int cnt = 0;
    for (int i = threadIdx.x; i < 4000; i += 256)
        if (e[2 * i + 1] != 0) cnt++;
    if (cnt) atomicAdd(&nz, cnt);
    __syncthreads();
    if (threadIdx.x == 0) *flag = (nz == 0) ? 1 : 0;  // 1 => data is int64
}

// ---------- repack edges + degree count (fused) ----------
__global__ __launch_bounds__(256) void repackdeg_kernel(const int* __restrict__ e, const int* __restrict__ flag,
                                                        int* __restrict__ srcI, int* __restrict__ dstI,
                                                        float* __restrict__ deg) {
    int i = blockIdx.x * 256 + threadIdx.x;
    if (i >= NE) return;
    int s, d;
    if (*flag) {
        s = e[2 * i];
        d = e[2 * (NE + i)];
    } else {
        s = e[i];
        d = e[NE + i];
    }
    srcI[i] = s;
    dstI[i] = d;
    atomicAdd(&deg[d], 1.0f);
}

__global__ __launch_bounds__(256) void deginv_kernel(float* __restrict__ deg) {
    int i = blockIdx.x * 256 + threadIdx.x;
    if (i < NN) deg[i] = (deg[i] > 0.f) ? (1.0f / deg[i]) : 0.f;
}

// ---------- W1 -> bf16 (128 x KP, zero-padded) ----------
__global__ __launch_bounds__(256) void convw_kernel(const float* __restrict__ Wl, const float* __restrict__ Wr,
                                                    u16* __restrict__ Wb) {
    int gid = blockIdx.x * 256 + threadIdx.x;
    if (gid >= 128 * (KP / 8)) return;
    int r = gid / (KP / 8), k0 = (gid % (KP / 8)) * 8;
    const float* srcw = (r < 64) ? (Wl + r * KD) : (Wr + (r - 64) * KD);
    u16 u[8];
    #pragma unroll
    for (int i = 0; i < 8; ++i) {
        int k = k0 + i;
        u[i] = (k < KD) ? f2bf(srcw[k]) : (u16)0;
    }
    *(uint4*)&Wb[r * KP + k0] = *(const uint4*)u;
}

// ---------- layer-1 MFMA GEMM v3 ----------
// x LDS-staged coalesced; W-frags direct from L2; NO atomics (partial buffers).
// grid (313, 2): 32 rows/block, K-chunk 768. yp[sk][n][128].
__global__ __launch_bounds__(256) void mm1_mfma(const float* __restrict__ x, const u16* __restrict__ Wb,
                                                float* __restrict__ yp) {
    __shared__ u16 XT[2][32 * 72];  // stride 72 elems (144B): 16B-aligned, bank-uniform
    const int t = threadIdx.x;
    const int w = t >> 6, lane = t & 63;
    const int n0 = blockIdx.x * 32;
    const int kc0 = blockIdx.y * KC;

    const int arow = lane & 15, ag = lane >> 4;
    const int mrow0 = (w & 1) * 16;       // wave's row offset within block tile
    const int c0 = (w >> 1) * 64;         // wave's col offset (of 128)

    // staging map: thread -> row sr = t>>3, 8 floats at col sg*8
    const int sr = t >> 3, sg = t & 7;
    int srow = n0 + sr;
    if (srow >= NN) srow = NN - 1;
    const float* xp = x + (size_t)srow * KD + kc0 + sg * 8;
    const int sdst = sr * 72 + sg * 8;    // element offset in XT[buf]

    // W pointer: frag f reads row c0 + f*16 + arow, 8 bf16 at k-offset ag*8
    const u16* wp = Wb + (size_t)(c0 + arow) * KP + kc0 + ag * 8;

    // A read: row mrow0 + arow, element offset (p*4+ag)*8 within stage
    const int aoff = (mrow0 + arow) * 72 + ag * 8;

    f32x4 acc[4] = {};

    // stage s into buffer b
    auto stage = [&](int s, int b) {
        int kc = kc0 + s * KSTEP + sg * 8;
        u16 u[8];
        if (kc + 7 < KD) {
            f32x4u v0 = *(const f32x4u*)(xp + s * KSTEP);
            f32x4u v1 = *(const f32x4u*)(xp + s * KSTEP + 4);
            u[0] = f2bf(v0.x); u[1] = f2bf(v0.y); u[2] = f2bf(v0.z); u[3] = f2bf(v0.w);
            u[4] = f2bf(v1.x); u[5] = f2bf(v1.y); u[6] = f2bf(v1.z); u[7] = f2bf(v1.w);
        } else {
            #pragma unroll
            for (int i = 0; i < 8; ++i)
                u[i] = (kc + i < KD) ? f2bf(xp[s * KSTEP + i]) : (u16)0;
        }
        *(uint4*)&XT[b][sdst] = *(const uint4*)u;
    };

    stage(0, 0);
    __syncthreads();

    for (int s = 0; s < NSTG; ++s) {
        if (s + 1 < NSTG) stage(s + 1, (s + 1) & 1);
        const u16* xbuf = &XT[s & 1][0];
        #pragma unroll
        for (int p = 0; p < 2; ++p) {
            bf16x8 af = *(const bf16x8*)&xbuf[aoff + p * 32];
            #pragma unroll
            for (int f = 0; f < 4; ++f) {
                bf16x8 bfr = *(const bf16x8*)(wp + (size_t)f * 16 * KP + s * KSTEP + p * 32);
                acc[f] = __builtin_amdgcn_mfma_f32_16x16x32_bf16(af, bfr, acc[f], 0, 0, 0);
            }
        }
        __syncthreads();
    }

    // C/D layout: col = lane&15, row = ag*4 + j ; plain stores to partial buffer
    float* ypb = yp + (size_t)blockIdx.y * NN * 128;
    #pragma unroll
    for (int f = 0; f < 4; ++f) {
        #pragma unroll
        for (int j = 0; j < 4; ++j) {
            int n = n0 + mrow0 + ag * 4 + j;
            int col = c0 + f * 16 + arow;
            if (n < NN) ypb[n * 128 + col] = acc[f][j];
        }
    }
}

// ---------- reduce split-K partials: y = yp0 + yp1 ----------
__global__ __launch_bounds__(256) void yreduce_kernel(const float* __restrict__ yp, float* __restrict__ y) {
    int i = blockIdx.x * 256 + threadIdx.x;
    if (i >= NN * 128 / 4) return;
    f32x4u a = ((const f32x4u*)yp)[i];
    f32x4u b = ((const f32x4u*)(yp + (size_t)NN * 128))[i];
    a.x += b.x; a.y += b.y; a.z += b.z; a.w += b.w;
    ((f32x4u*)y)[i] = a;
}

// ---------- fused combine + GEMM for layers 2/3 ----------
template<int DIN>
__global__ __launch_bounds__(256) void mm23_fused(const float* __restrict__ agg, const float* __restrict__ yprev,
                                                  const float* __restrict__ deg_inv, const float* __restrict__ b,
                                                  const float* __restrict__ Wl, const float* __restrict__ Wr,
                                                  float* __restrict__ yout) {
    __shared__ float Xs[32][DIN + 1];
    __shared__ float Ws[64][DIN + 1];
    const int t = threadIdx.x;
    const int n0 = blockIdx.x * 32;
    #pragma unroll
    for (int i = 0; i < (64 * DIN) / 256; ++i) {
        int e = t + i * 256;
        int row = e / DIN, col = e % DIN;
        Ws[row][col] = (row < 32) ? Wl[row * DIN + col] : Wr[(row - 32) * DIN + col];
    }
    #pragma unroll
    for (int i = 0; i < (32 * DIN) / 256; ++i) {
        int e = t + i * 256;
        int r = e / DIN, d = e % DIN;
        int n = n0 + r;
        float v = 0.f;
        if (n < NN)
            v = fmaxf(agg[n * DIN + d] * deg_inv[n] + b[d] + yprev[n * 2 * DIN + DIN + d], 0.f);
        Xs[r][d] = v;
    }
    __syncthreads();
    const int tr = t >> 5;
    const int tc = t & 31;
    float acc[4][2] = {};
    #pragma unroll 4
    for (int k = 0; k < DIN; ++k) {
        float xv[4], wv[2];
        #pragma unroll
        for (int r = 0; r < 4; ++r) xv[r] = Xs[tr * 4 + r][k];
        wv[0] = Ws[tc * 2][k];
        wv[1] = Ws[tc * 2 + 1][k];
        #pragma unroll
        for (int r = 0; r < 4; ++r) {
            acc[r][0] = fmaf(xv[r], wv[0], acc[r][0]);
            acc[r][1] = fmaf(xv[r], wv[1], acc[r][1]);
        }
    }
    #pragma unroll
    for (int r = 0; r < 4; ++r) {
        int n = n0 + tr * 4 + r;
        if (n < NN) {
            yout[n * 64 + tc * 2]     = acc[r][0];
            yout[n * 64 + tc * 2 + 1] = acc[r][1];
        }
    }
}

// ---------- edge scatter: agg[dst] += y_l[src] ----------
template<int DIM, int YSTRIDE>
__global__ __launch_bounds__(256) void agg_kernel(const float* __restrict__ y, const int* __restrict__ src,
                                                  const int* __restrict__ dst, float* __restrict__ agg) {
    int gid = blockIdx.x * 256 + threadIdx.x;
    int e = gid / DIM, d = gid % DIM;
    if (e >= NE) return;
    atomicAdd(&agg[dst[e] * DIM + d], y[src[e] * YSTRIDE + d]);
}

// ---------- fused combine3 + post_mp + log_softmax ----------
__global__ __launch_bounds__(256) void final_fused(const float* __restrict__ agg, const float* __restrict__ y3,
                                                   const float* __restrict__ deg_inv, const float* __restrict__ b3,
                                                   const float* __restrict__ M1w, const float* __restrict__ M1b,
                                                   const float* __restrict__ M2w, const float* __restrict__ M2b,
                                                   float* __restrict__ out) {
    int wv = (blockIdx.x * 256 + threadIdx.x) >> 6;
    int lane = threadIdx.x & 63;
    if (wv >= NN) return;  // uniform per wave
    float hv = 0.f;
    if (lane < 32)
        hv = fmaxf(agg[wv * 32 + lane] * deg_inv[wv] + b3[lane] + y3[wv * 64 + 32 + lane], 0.f);
    float tv = (lane < 32) ? M1b[lane] : 0.f;
    #pragma unroll 8
    for (int k = 0; k < 32; ++k) {
        float hk = __shfl(hv, k, 64);
        if (lane < 32) tv = fmaf(hk, M1w[lane * 32 + k], tv);
    }
    float uv = (lane < 7) ? M2b[lane] : 0.f;
    #pragma unroll 8
    for (int k = 0; k < 32; ++k) {
        float tk = __shfl(tv, k, 64);
        if (lane < 7) uv = fmaf(tk, M2w[lane * 32 + k], uv);
    }
    float m = -1e30f;
    float uc[7];
    #pragma unroll
    for (int c = 0; c < 7; ++c) { uc[c] = __shfl(uv, c, 64); m = fmaxf(m, uc[c]); }
    float s = 0.f;
    #pragma unroll
    for (int c = 0; c < 7; ++c) s += expf(uc[c] - m);
    float lse = m + logf(s);
    if (lane < 7) out[wv * 7 + lane] = uv - lse;
}

extern "C" void kernel_launch(void* const* d_in, const int* in_sizes, int n_in,
                              void* d_out, int out_size, void* d_ws, size_t ws_size,
                              hipStream_t stream) {
    const float* x   = (const float*)d_in[0];
    const int*   eix = (const int*)d_in[1];
    const float* W1l = (const float*)d_in[2];
    const float* b1  = (const float*)d_in[3];
    const float* W1r = (const float*)d_in[4];
    const float* W2l = (const float*)d_in[5];
    const float* b2  = (const float*)d_in[6];
    const float* W2r = (const float*)d_in[7];
    const float* W3l = (const float*)d_in[8];
    const float* b3  = (const float*)d_in[9];
    const float* W3r = (const float*)d_in[10];
    const float* M1w = (const float*)d_in[11];
    const float* M1b = (const float*)d_in[12];
    const float* M2w = (const float*)d_in[13];
    const float* M2b = (const float*)d_in[14];
    float* out = (float*)d_out;

    char* w = (char*)d_ws;
    int*   flag = (int*)w;    w += 256;
    int*   srcI = (int*)w;    w += NE * 4;
    int*   dstI = (int*)w;    w += NE * 4;
    float* deg  = (float*)w;  w += 40960;
    // zero block: agg1 | agg2 | agg3 (one memset)
    float* agg1 = (float*)w;  w += NN * 64 * 4;
    float* agg2 = (float*)w;  w += NN * 32 * 4;
    float* agg3 = (float*)w;  w += NN * 32 * 4;
    float* y    = (float*)w;  w += NN * 128 * 4;
    float* yp   = (float*)w;  w += (size_t)SK1 * NN * 128 * 4;
    float* y2   = (float*)w;  w += NN * 64 * 4;
    float* y3   = (float*)w;  w += NN * 64 * 4;
    u16*   Wb   = (u16*)w;    w += 128 * KP * 2;

    detect_kernel<<<1, 256, 0, stream>>>(eix, flag);
    hipMemsetAsync(deg, 0, NN * 4, stream);
    repackdeg_kernel<<<(NE + 255) / 256, 256, 0, stream>>>(eix, flag, srcI, dstI, deg);
    deginv_kernel<<<(NN + 255) / 256, 256, 0, stream>>>(deg);

    convw_kernel<<<(128 * (KP / 8) + 255) / 256, 256, 0, stream>>>(W1l, W1r, Wb);

    hipMemsetAsync(agg1, 0, (size_t)NN * 128 * 4, stream);  // agg1+agg2+agg3

    // layer 1: no atomics, partial buffers + reduce
    {
        dim3 grid((NN + 31) / 32, SK1);
        mm1_mfma<<<grid, 256, 0, stream>>>(x, Wb, yp);
    }
    yreduce_kernel<<<(NN * 128 / 4 + 255) / 256, 256, 0, stream>>>(yp, y);
    agg_kernel<64, 128><<<(NE * 64) / 256, 256, 0, stream>>>(y, srcI, dstI, agg1);

    // layer 2 (combine fused into GEMM staging)
    mm23_fused<64><<<(NN + 31) / 32, 256, 0, stream>>>(agg1, y, deg, b1, W2l, W2r, y2);
    agg_kernel<32, 64><<<(NE * 32) / 256, 256, 0, stream>>>(y2, srcI, dstI, agg2);

    // layer 3
    mm23_fused<32><<<(NN + 31) / 32, 256, 0, stream>>>(agg2, y2, deg, b2, W3l, W3r, y3);
    agg_kernel<32, 64><<<(NE * 32) / 256, 256, 0, stream>>>(y3, srcI, dstI, agg3);

    // combine3 + post_mp + log_softmax
    final_fused<<<(NN + 3) / 4, 256, 0, stream>>>(agg3, y3, deg, b3, M1w, M1b, M2w, M2b, out);
}

// Round 9
// 191.800 us; speedup vs baseline: 1.0179x; 1.0179x over previous
//
#include <hip/hip_runtime.h>

#define NN 10000
#define NE 160000
#define KD 1433
#define KP 1536     // padded K (zero-filled in Wb)
#define KST 128     // K per LDS stage
#define NKS 12      // KP/KST
#define ASTR 136    // LDS row stride in elems (272B, 16B-aligned)

typedef unsigned short u16;
typedef __attribute__((ext_vector_type(4))) float f32x4;
typedef __attribute__((ext_vector_type(8))) short bf16x8;
typedef __attribute__((ext_vector_type(4), aligned(4))) float f32x4u;

__device__ __forceinline__ u16 f2bf(float f) {
    union { float f; unsigned u; } v; v.f = f;
    unsigned r = (v.u + 0x7FFF + ((v.u >> 16) & 1)) >> 16;
    return (u16)r;
}

// ---------- edge dtype detect ----------
__global__ __launch_bounds__(256) void detect_kernel(const int* __restrict__ e, int* __restrict__ flag) {
    __shared__ int nz;
    if (threadIdx.x == 0) nz = 0;
    __syncthreads();
    int cnt = 0;
    for (int i = threadIdx.x; i < 4000; i += 256)
        if (e[2 * i + 1] != 0) cnt++;
    if (cnt) atomicAdd(&nz, cnt);
    __syncthreads();
    if (threadIdx.x == 0) *flag = (nz == 0) ? 1 : 0;  // 1 => data is int64
}

// ---------- repack edges + degree count (fused) ----------
__global__ __launch_bounds__(256) void repackdeg_kernel(const int* __restrict__ e, const int* __restrict__ flag,
                                                        int* __restrict__ srcI, int* __restrict__ dstI,
                                                        float* __restrict__ deg) {
    int i = blockIdx.x * 256 + threadIdx.x;
    if (i >= NE) return;
    int s, d;
    if (*flag) {
        s = e[2 * i];
        d = e[2 * (NE + i)];
    } else {
        s = e[i];
        d = e[NE + i];
    }
    srcI[i] = s;
    dstI[i] = d;
    atomicAdd(&deg[d], 1.0f);
}

__global__ __launch_bounds__(256) void deginv_kernel(float* __restrict__ deg) {
    int i = blockIdx.x * 256 + threadIdx.x;
    if (i < NN) deg[i] = (deg[i] > 0.f) ? (1.0f / deg[i]) : 0.f;
}

// ---------- W1 -> bf16 (128 x KP, zero-padded) ----------
__global__ __launch_bounds__(256) void convw_kernel(const float* __restrict__ Wl, const float* __restrict__ Wr,
                                                    u16* __restrict__ Wb) {
    int gid = blockIdx.x * 256 + threadIdx.x;
    if (gid >= 128 * (KP / 8)) return;
    int r = gid / (KP / 8), k0 = (gid % (KP / 8)) * 8;
    const float* srcw = (r < 64) ? (Wl + r * KD) : (Wr + (r - 64) * KD);
    u16 u[8];
    #pragma unroll
    for (int i = 0; i < 8; ++i) {
        int k = k0 + i;
        u[i] = (k < KD) ? f2bf(srcw[k]) : (u16)0;
    }
    *(uint4*)&Wb[r * KP + k0] = *(const uint4*)u;
}

// ---------- layer-1 MFMA GEMM v4: ALL-COALESCED staging, both operands LDS ----------
// grid (313, 2): block = 32 rows x 64 cols (col half), full K. Plain disjoint stores.
__global__ __launch_bounds__(256) void mm1_mfma(const float* __restrict__ x, const u16* __restrict__ Wb,
                                                float* __restrict__ y) {
    __shared__ u16 AT[2][32 * ASTR];
    __shared__ u16 WT[2][64 * ASTR];
    const int t = threadIdx.x;
    const int w = t >> 6, lane = t & 63;
    const int n0 = blockIdx.x * 32;
    const int c0 = blockIdx.y * 64;

    // A staging: thread -> row sr=t>>3 (8 thr/row), 16B-unit q=t&7; 4 loads i: byte (q+8i)*16
    const int sr = t >> 3, q = t & 7;
    int srow = n0 + sr;
    if (srow >= NN) srow = NN - 1;
    const float* xp = x + (size_t)srow * KD;

    // W staging: thread -> row wrr=t>>2 (4 thr/row), p=t&3; 4 loads j: byte p*16 + j*64
    const int wrr = t >> 2, p = t & 3;
    const u16* wp = Wb + (size_t)(c0 + wrr) * KP;

    // fragment addressing
    const int fr = lane & 15, hi = lane >> 4;
    const int a_base = ((w & 1) * 16 + fr) * ASTR + hi * 8;   // + slice*32
    const int b_base0 = ((w >> 1) * 32 + fr) * ASTR + hi * 8;
    const int b_base1 = b_base0 + 16 * ASTR;

    f32x4 acc[2] = {};

    float4 la[4];
    uint4  lw[4];

    auto stage_load = [&](int ks) {
        const int kc = ks * KST;
        #pragma unroll
        for (int i = 0; i < 4; ++i) {
            int col = kc + (q + 8 * i) * 4;
            if (col + 3 < KD) {
                f32x4u v = *(const f32x4u*)(xp + col);
                la[i] = make_float4(v.x, v.y, v.z, v.w);
            } else {
                float tv[4];
                #pragma unroll
                for (int u2 = 0; u2 < 4; ++u2) tv[u2] = (col + u2 < KD) ? xp[col + u2] : 0.f;
                la[i] = make_float4(tv[0], tv[1], tv[2], tv[3]);
            }
        }
        const u16* wpk = wp + kc;
        #pragma unroll
        for (int j = 0; j < 4; ++j)
            lw[j] = *(const uint4*)(wpk + p * 8 + j * 32);
    };

    auto stage_write = [&](int b) {
        #pragma unroll
        for (int i = 0; i < 4; ++i) {
            u16 u2[4] = { f2bf(la[i].x), f2bf(la[i].y), f2bf(la[i].z), f2bf(la[i].w) };
            *(uint2*)&AT[b][sr * ASTR + (q + 8 * i) * 4] = *(const uint2*)u2;
        }
        #pragma unroll
        for (int j = 0; j < 4; ++j)
            *(uint4*)&WT[b][wrr * ASTR + p * 8 + j * 32] = lw[j];
    };

    stage_load(0);
    stage_write(0);
    __syncthreads();

    for (int ks = 0; ks < NKS; ++ks) {
        const bool more = (ks + 1 < NKS);
        if (more) stage_load(ks + 1);
        const u16* ab = &AT[ks & 1][0];
        const u16* wb2 = &WT[ks & 1][0];
        #pragma unroll
        for (int s = 0; s < 4; ++s) {
            bf16x8 af = *(const bf16x8*)&ab[a_base + s * 32];
            bf16x8 bf0 = *(const bf16x8*)&wb2[b_base0 + s * 32];
            bf16x8 bf1 = *(const bf16x8*)&wb2[b_base1 + s * 32];
            acc[0] = __builtin_amdgcn_mfma_f32_16x16x32_bf16(af, bf0, acc[0], 0, 0, 0);
            acc[1] = __builtin_amdgcn_mfma_f32_16x16x32_bf16(af, bf1, acc[1], 0, 0, 0);
        }
        if (more) stage_write((ks + 1) & 1);
        __syncthreads();
    }

    // C/D layout: col = lane&15, row = hi*4 + j ; disjoint plain stores
    #pragma unroll
    for (int f = 0; f < 2; ++f) {
        #pragma unroll
        for (int j = 0; j < 4; ++j) {
            int n = n0 + (w & 1) * 16 + hi * 4 + j;
            int col = c0 + (w >> 1) * 32 + f * 16 + fr;
            if (n < NN) y[n * 128 + col] = acc[f][j];
        }
    }
}

// ---------- fused combine + GEMM for layers 2/3 ----------
template<int DIN>
__global__ __launch_bounds__(256) void mm23_fused(const float* __restrict__ agg, const float* __restrict__ yprev,
                                                  const float* __restrict__ deg_inv, const float* __restrict__ b,
                                                  const float* __restrict__ Wl, const float* __restrict__ Wr,
                                                  float* __restrict__ yout) {
    __shared__ float Xs[32][DIN + 1];
    __shared__ float Ws[64][DIN + 1];
    const int t = threadIdx.x;
    const int n0 = blockIdx.x * 32;
    #pragma unroll
    for (int i = 0; i < (64 * DIN) / 256; ++i) {
        int e = t + i * 256;
        int row = e / DIN, col = e % DIN;
        Ws[row][col] = (row < 32) ? Wl[row * DIN + col] : Wr[(row - 32) * DIN + col];
    }
    #pragma unroll
    for (int i = 0; i < (32 * DIN) / 256; ++i) {
        int e = t + i * 256;
        int r = e / DIN, d = e % DIN;
        int n = n0 + r;
        float v = 0.f;
        if (n < NN)
            v = fmaxf(agg[n * DIN + d] * deg_inv[n] + b[d] + yprev[n * 2 * DIN + DIN + d], 0.f);
        Xs[r][d] = v;
    }
    __syncthreads();
    const int tr = t >> 5;
    const int tc = t & 31;
    float acc[4][2] = {};
    #pragma unroll 4
    for (int k = 0; k < DIN; ++k) {
        float xv[4], wv[2];
        #pragma unroll
        for (int r = 0; r < 4; ++r) xv[r] = Xs[tr * 4 + r][k];
        wv[0] = Ws[tc * 2][k];
        wv[1] = Ws[tc * 2 + 1][k];
        #pragma unroll
        for (int r = 0; r < 4; ++r) {
            acc[r][0] = fmaf(xv[r], wv[0], acc[r][0]);
            acc[r][1] = fmaf(xv[r], wv[1], acc[r][1]);
        }
    }
    #pragma unroll
    for (int r = 0; r < 4; ++r) {
        int n = n0 + tr * 4 + r;
        if (n < NN) {
            yout[n * 64 + tc * 2]     = acc[r][0];
            yout[n * 64 + tc * 2 + 1] = acc[r][1];
        }
    }
}

// ---------- edge scatter: agg[dst] += y_l[src] ----------
template<int DIM, int YSTRIDE>
__global__ __launch_bounds__(256) void agg_kernel(const float* __restrict__ y, const int* __restrict__ src,
                                                  const int* __restrict__ dst, float* __restrict__ agg) {
    int gid = blockIdx.x * 256 + threadIdx.x;
    int e = gid / DIM, d = gid % DIM;
    if (e >= NE) return;
    atomicAdd(&agg[dst[e] * DIM + d], y[src[e] * YSTRIDE + d]);
}

// ---------- fused combine3 + post_mp + log_softmax ----------
__global__ __launch_bounds__(256) void final_fused(const float* __restrict__ agg, const float* __restrict__ y3,
                                                   const float* __restrict__ deg_inv, const float* __restrict__ b3,
                                                   const float* __restrict__ M1w, const float* __restrict__ M1b,
                                                   const float* __restrict__ M2w, const float* __restrict__ M2b,
                                                   float* __restrict__ out) {
    int wv = (blockIdx.x * 256 + threadIdx.x) >> 6;
    int lane = threadIdx.x & 63;
    if (wv >= NN) return;  // uniform per wave
    float hv = 0.f;
    if (lane < 32)
        hv = fmaxf(agg[wv * 32 + lane] * deg_inv[wv] + b3[lane] + y3[wv * 64 + 32 + lane], 0.f);
    float tv = (lane < 32) ? M1b[lane] : 0.f;
    #pragma unroll 8
    for (int k = 0; k < 32; ++k) {
        float hk = __shfl(hv, k, 64);
        if (lane < 32) tv = fmaf(hk, M1w[lane * 32 + k], tv);
    }
    float uv = (lane < 7) ? M2b[lane] : 0.f;
    #pragma unroll 8
    for (int k = 0; k < 32; ++k) {
        float tk = __shfl(tv, k, 64);
        if (lane < 7) uv = fmaf(tk, M2w[lane * 32 + k], uv);
    }
    float m = -1e30f;
    float uc[7];
    #pragma unroll
    for (int c = 0; c < 7; ++c) { uc[c] = __shfl(uv, c, 64); m = fmaxf(m, uc[c]); }
    float s = 0.f;
    #pragma unroll
    for (int c = 0; c < 7; ++c) s += expf(uc[c] - m);
    float lse = m + logf(s);
    if (lane < 7) out[wv * 7 + lane] = uv - lse;
}

extern "C" void kernel_launch(void* const* d_in, const int* in_sizes, int n_in,
                              void* d_out, int out_size, void* d_ws, size_t ws_size,
                              hipStream_t stream) {
    const float* x   = (const float*)d_in[0];
    const int*   eix = (const int*)d_in[1];
    const float* W1l = (const float*)d_in[2];
    const float* b1  = (const float*)d_in[3];
    const float* W1r = (const float*)d_in[4];
    const float* W2l = (const float*)d_in[5];
    const float* b2  = (const float*)d_in[6];
    const float* W2r = (const float*)d_in[7];
    const float* W3l = (const float*)d_in[8];
    const float* b3  = (const float*)d_in[9];
    const float* W3r = (const float*)d_in[10];
    const float* M1w = (const float*)d_in[11];
    const float* M1b = (const float*)d_in[12];
    const float* M2w = (const float*)d_in[13];
    const float* M2b = (const float*)d_in[14];
    float* out = (float*)d_out;

    char* w = (char*)d_ws;
    int*   flag = (int*)w;    w += 256;
    int*   srcI = (int*)w;    w += NE * 4;
    int*   dstI = (int*)w;    w += NE * 4;
    float* deg  = (float*)w;  w += 40960;
    // zero block: agg1 | agg2 | agg3 (one memset)
    float* agg1 = (float*)w;  w += NN * 64 * 4;
    float* agg2 = (float*)w;  w += NN * 32 * 4;
    float* agg3 = (float*)w;  w += NN * 32 * 4;
    float* y    = (float*)w;  w += NN * 128 * 4;
    float* y2   = (float*)w;  w += NN * 64 * 4;
    float* y3   = (float*)w;  w += NN * 64 * 4;
    u16*   Wb   = (u16*)w;    w += 128 * KP * 2;

    detect_kernel<<<1, 256, 0, stream>>>(eix, flag);
    hipMemsetAsync(deg, 0, NN * 4, stream);
    repackdeg_kernel<<<(NE + 255) / 256, 256, 0, stream>>>(eix, flag, srcI, dstI, deg);
    deginv_kernel<<<(NN + 255) / 256, 256, 0, stream>>>(deg);

    convw_kernel<<<(128 * (KP / 8) + 255) / 256, 256, 0, stream>>>(W1l, W1r, Wb);

    hipMemsetAsync(agg1, 0, (size_t)NN * 128 * 4, stream);  // agg1+agg2+agg3

    // layer 1: all-coalesced, no atomics, no reduce
    {
        dim3 grid((NN + 31) / 32, 2);
        mm1_mfma<<<grid, 256, 0, stream>>>(x, Wb, y);
    }
    agg_kernel<64, 128><<<(NE * 64) / 256, 256, 0, stream>>>(y, srcI, dstI, agg1);

    // layer 2 (combine fused into GEMM staging)
    mm23_fused<64><<<(NN + 31) / 32, 256, 0, stream>>>(agg1, y, deg, b1, W2l, W2r, y2);
    agg_kernel<32, 64><<<(NE * 32) / 256, 256, 0, stream>>>(y2, srcI, dstI, agg2);

    // layer 3
    mm23_fused<32><<<(NN + 31) / 32, 256, 0, stream>>>(agg2, y2, deg, b2, W3l, W3r, y3);
    agg_kernel<32, 64><<<(NE * 32) / 256, 256, 0, stream>>>(y3, srcI, dstI, agg3);

    // combine3 + post_mp + log_softmax
    final_fused<<<(NN + 3) / 4, 256, 0, stream>>>(agg3, y3, deg, b3, M1w, M1b, M2w, M2b, out);
}

// Round 10
// 176.403 us; speedup vs baseline: 1.1067x; 1.0873x over previous
//
#include <hip/hip_runtime.h>

#define NN 10000
#define NE 160000
#define KD 1433
#define KP 1536    // padded K (zero-filled in Wb)
#define SK1 2      // split-K (partial buffers, no atomics)
#define KC 768     // K per block
#define KSTEP 64   // K per LDS stage
#define NST 12     // KC/KSTEP

typedef unsigned short u16;
typedef __attribute__((ext_vector_type(4))) float f32x4;
typedef __attribute__((ext_vector_type(8))) short bf16x8;
typedef __attribute__((ext_vector_type(4), aligned(4))) float f32x4u;

__device__ __forceinline__ u16 f2bf(float f) {
    union { float f; unsigned u; } v; v.f = f;
    unsigned r = (v.u + 0x7FFF + ((v.u >> 16) & 1)) >> 16;
    return (u16)r;
}

// async global->LDS, 16B per lane: per-lane global src, wave-uniform LDS base (+lane*16)
__device__ __forceinline__ void gload16(const void* g, void* l) {
    __builtin_amdgcn_global_load_lds(
        (__attribute__((address_space(1))) void*)(void*)g,
        (__attribute__((address_space(3))) void*)l, 16, 0, 0);
}

// ---------- edge dtype detect ----------
__global__ __launch_bounds__(256) void detect_kernel(const int* __restrict__ e, int* __restrict__ flag) {
    __shared__ int nz;
    if (threadIdx.x == 0) nz = 0;
    __syncthreads();
    int cnt = 0;
    for (int i = threadIdx.x; i < 4000; i += 256)
        if (e[2 * i + 1] != 0) cnt++;
    if (cnt) atomicAdd(&nz, cnt);
    __syncthreads();
    if (threadIdx.x == 0) *flag = (nz == 0) ? 1 : 0;  // 1 => data is int64
}

// ---------- repack edges + degree count (fused) ----------
__global__ __launch_bounds__(256) void repackdeg_kernel(const int* __restrict__ e, const int* __restrict__ flag,
                                                        int* __restrict__ srcI, int* __restrict__ dstI,
                                                        float* __restrict__ deg) {
    int i = blockIdx.x * 256 + threadIdx.x;
    if (i >= NE) return;
    int s, d;
    if (*flag) {
        s = e[2 * i];
        d = e[2 * (NE + i)];
    } else {
        s = e[i];
        d = e[NE + i];
    }
    srcI[i] = s;
    dstI[i] = d;
    atomicAdd(&deg[d], 1.0f);
}

__global__ __launch_bounds__(256) void deginv_kernel(float* __restrict__ deg) {
    int i = blockIdx.x * 256 + threadIdx.x;
    if (i < NN) deg[i] = (deg[i] > 0.f) ? (1.0f / deg[i]) : 0.f;
}

// ---------- W1 -> bf16 (128 x KP, zero-padded) ----------
__global__ __launch_bounds__(256) void convw_kernel(const float* __restrict__ Wl, const float* __restrict__ Wr,
                                                    u16* __restrict__ Wb) {
    int gid = blockIdx.x * 256 + threadIdx.x;
    if (gid >= 128 * (KP / 8)) return;
    int r = gid / (KP / 8), k0 = (gid % (KP / 8)) * 8;
    const float* srcw = (r < 64) ? (Wl + r * KD) : (Wr + (r - 64) * KD);
    u16 u[8];
    #pragma unroll
    for (int i = 0; i < 8; ++i) {
        int k = k0 + i;
        u[i] = (k < KD) ? f2bf(srcw[k]) : (u16)0;
    }
    *(uint4*)&Wb[r * KP + k0] = *(const uint4*)u;
}

// ---------- layer-1 MFMA GEMM v5: global_load_lds staging, pre-swizzled sources ----------
// grid (313, 2): 32 rows x 128 cols per block, K-chunk 768. Plain stores to yp partials.
__global__ __launch_bounds__(256) void mm1_mfma(const float* __restrict__ x, const u16* __restrict__ Wb,
                                                float* __restrict__ yp) {
    __shared__ float AT[2][2048];   // 8KB/buf: 8 pages x (4 rows x 64 floats)
    __shared__ u16  WT[2][8192];    // 16KB/buf: 16 pages x (8 rows x 64 bf16)
    const int t = threadIdx.x;
    const int w = t >> 6, lane = t & 63;
    const int n0 = blockIdx.x * 32;
    const int kc0 = blockIdx.y * KC;

    // ---- staging source addresses (per wave: 2 A-insts + 4 W-insts, 1KB each) ----
    // A inst i: lane -> row 4i+(lane>>4), global chunk q = c ^ (rowin<<2) ^ (i&3)  [4 floats/chunk]
    const int rowinA = lane >> 4;           // 0..3
    const int cA = lane & 15;
    size_t aoff[2];
    #pragma unroll
    for (int ii = 0; ii < 2; ++ii) {
        int i = 2 * w + ii;
        int r = 4 * i + rowinA;             // 0..31
        int grow = n0 + r; if (grow >= NN) grow = NN - 1;
        int q = cA ^ (rowinA << 2) ^ (i & 3);
        aoff[ii] = (size_t)grow * KD + (size_t)kc0 + (size_t)(q * 4);
    }
    const size_t amax = (size_t)NN * KD - 4;
    // W inst j: lane -> row 8j+(lane>>3), global chunk qw = c ^ (rowin&7)  [8 bf16/chunk]
    const int rowinW = lane >> 3;           // 0..7
    const int qw = (lane & 7) ^ rowinW;
    size_t woff[4];
    #pragma unroll
    for (int jj = 0; jj < 4; ++jj) {
        int j = 4 * w + jj;
        int r = 8 * j + rowinW;             // 0..127
        woff[jj] = (size_t)r * KP + (size_t)kc0 + (size_t)(qw * 8);
    }

    // ---- fragment addressing ----
    const int fr = lane & 15, hi = lane >> 4;
    const int ar0 = (w & 1) * 16;           // wave's A-row offset
    const int c0w = (w >> 1) * 64;          // wave's col offset
    const int arow = ar0 + fr;
    const int apage = (arow >> 2) * 256 + (arow & 3) * 64;
    const int asw = ((arow & 3) << 2) ^ ((arow >> 2) & 3);

    f32x4 acc[4] = {};

    auto stage = [&](int s, int b) {
        const int ko = s * KSTEP;
        #pragma unroll
        for (int ii = 0; ii < 2; ++ii) {
            size_t o = aoff[ii] + ko;
            if (o > amax) o = amax;
            gload16(x + o, &AT[b][(2 * w + ii) * 256]);
        }
        #pragma unroll
        for (int jj = 0; jj < 4; ++jj)
            gload16(Wb + woff[jj] + ko, &WT[b][(4 * w + jj) * 512]);
    };

    stage(0, 0);
    __syncthreads();   // drains vmcnt -> buf0 ready

    for (int s = 0; s < NST; ++s) {
        if (s + 1 < NST) stage(s + 1, (s + 1) & 1);
        const float* ab = &AT[s & 1][0];
        const u16* wbuf = &WT[s & 1][0];
        #pragma unroll
        for (int p = 0; p < 2; ++p) {
            const int q0 = p * 8 + hi * 2;
            f32x4 alo = *(const f32x4*)&ab[apage + ((q0    ) ^ asw) * 4];
            f32x4 ahi = *(const f32x4*)&ab[apage + ((q0 + 1) ^ asw) * 4];
            u16 au[8] = { f2bf(alo[0]), f2bf(alo[1]), f2bf(alo[2]), f2bf(alo[3]),
                          f2bf(ahi[0]), f2bf(ahi[1]), f2bf(ahi[2]), f2bf(ahi[3]) };
            bf16x8 af = *(const bf16x8*)au;
            #pragma unroll
            for (int f = 0; f < 4; ++f) {
                int wrow = c0w + f * 16 + fr;
                int kcw = (p * 4 + hi) ^ (wrow & 7);
                bf16x8 bfr = *(const bf16x8*)&wbuf[(wrow >> 3) * 512 + (wrow & 7) * 64 + kcw * 8];
                acc[f] = __builtin_amdgcn_mfma_f32_16x16x32_bf16(af, bfr, acc[f], 0, 0, 0);
            }
        }
        __syncthreads();  // drains stage(s+1) loads; releases buf s for next stage
    }

    // C/D layout: col = lane&15, row = hi*4 + j ; disjoint plain stores to partial buffer
    float* ypb = yp + (size_t)blockIdx.y * NN * 128;
    #pragma unroll
    for (int f = 0; f < 4; ++f) {
        #pragma unroll
        for (int j = 0; j < 4; ++j) {
            int n = n0 + ar0 + hi * 4 + j;
            int col = c0w + f * 16 + fr;
            if (n < NN) ypb[n * 128 + col] = acc[f][j];
        }
    }
}

// ---------- reduce split-K partials: y = yp0 + yp1 ----------
__global__ __launch_bounds__(256) void yreduce_kernel(const float* __restrict__ yp, float* __restrict__ y) {
    int i = blockIdx.x * 256 + threadIdx.x;
    if (i >= NN * 128 / 4) return;
    f32x4u a = ((const f32x4u*)yp)[i];
    f32x4u b = ((const f32x4u*)(yp + (size_t)NN * 128))[i];
    a.x += b.x; a.y += b.y; a.z += b.z; a.w += b.w;
    ((f32x4u*)y)[i] = a;
}

// ---------- fused combine + GEMM for layers 2/3 ----------
template<int DIN>
__global__ __launch_bounds__(256) void mm23_fused(const float* __restrict__ agg, const float* __restrict__ yprev,
                                                  const float* __restrict__ deg_inv, const float* __restrict__ b,
                                                  const float* __restrict__ Wl, const float* __restrict__ Wr,
                                                  float* __restrict__ yout) {
    __shared__ float Xs[32][DIN + 1];
    __shared__ float Ws[64][DIN + 1];
    const int t = threadIdx.x;
    const int n0 = blockIdx.x * 32;
    #pragma unroll
    for (int i = 0; i < (64 * DIN) / 256; ++i) {
        int e = t + i * 256;
        int row = e / DIN, col = e % DIN;
        Ws[row][col] = (row < 32) ? Wl[row * DIN + col] : Wr[(row - 32) * DIN + col];
    }
    #pragma unroll
    for (int i = 0; i < (32 * DIN) / 256; ++i) {
        int e = t + i * 256;
        int r = e / DIN, d = e % DIN;
        int n = n0 + r;
        float v = 0.f;
        if (n < NN)
            v = fmaxf(agg[n * DIN + d] * deg_inv[n] + b[d] + yprev[n * 2 * DIN + DIN + d], 0.f);
        Xs[r][d] = v;
    }
    __syncthreads();
    const int tr = t >> 5;
    const int tc = t & 31;
    float acc[4][2] = {};
    #pragma unroll 4
    for (int k = 0; k < DIN; ++k) {
        float xv[4], wv[2];
        #pragma unroll
        for (int r = 0; r < 4; ++r) xv[r] = Xs[tr * 4 + r][k];
        wv[0] = Ws[tc * 2][k];
        wv[1] = Ws[tc * 2 + 1][k];
        #pragma unroll
        for (int r = 0; r < 4; ++r) {
            acc[r][0] = fmaf(xv[r], wv[0], acc[r][0]);
            acc[r][1] = fmaf(xv[r], wv[1], acc[r][1]);
        }
    }
    #pragma unroll
    for (int r = 0; r < 4; ++r) {
        int n = n0 + tr * 4 + r;
        if (n < NN) {
            yout[n * 64 + tc * 2]     = acc[r][0];
            yout[n * 64 + tc * 2 + 1] = acc[r][1];
        }
    }
}

// ---------- edge scatter: agg[dst] += y_l[src] ----------
template<int DIM, int YSTRIDE>
__global__ __launch_bounds__(256) void agg_kernel(const float* __restrict__ y, const int* __restrict__ src,
                                                  const int* __restrict__ dst, float* __restrict__ agg) {
    int gid = blockIdx.x * 256 + threadIdx.x;
    int e = gid / DIM, d = gid % DIM;
    if (e >= NE) return;
    atomicAdd(&agg[dst[e] * DIM + d], y[src[e] * YSTRIDE + d]);
}

// ---------- fused combine3 + post_mp + log_softmax ----------
__global__ __launch_bounds__(256) void final_fused(const float* __restrict__ agg, const float* __restrict__ y3,
                                                   const float* __restrict__ deg_inv, const float* __restrict__ b3,
                                                   const float* __restrict__ M1w, const float* __restrict__ M1b,
                                                   const float* __restrict__ M2w, const float* __restrict__ M2b,
                                                   float* __restrict__ out) {
    int wv = (blockIdx.x * 256 + threadIdx.x) >> 6;
    int lane = threadIdx.x & 63;
    if (wv >= NN) return;  // uniform per wave
    float hv = 0.f;
    if (lane < 32)
        hv = fmaxf(agg[wv * 32 + lane] * deg_inv[wv] + b3[lane] + y3[wv * 64 + 32 + lane], 0.f);
    float tv = (lane < 32) ? M1b[lane] : 0.f;
    #pragma unroll 8
    for (int k = 0; k < 32; ++k) {
        float hk = __shfl(hv, k, 64);
        if (lane < 32) tv = fmaf(hk, M1w[lane * 32 + k], tv);
    }
    float uv = (lane < 7) ? M2b[lane] : 0.f;
    #pragma unroll 8
    for (int k = 0; k < 32; ++k) {
        float tk = __shfl(tv, k, 64);
        if (lane < 7) uv = fmaf(tk, M2w[lane * 32 + k], uv);
    }
    float m = -1e30f;
    float uc[7];
    #pragma unroll
    for (int c = 0; c < 7; ++c) { uc[c] = __shfl(uv, c, 64); m = fmaxf(m, uc[c]); }
    float s = 0.f;
    #pragma unroll
    for (int c = 0; c < 7; ++c) s += expf(uc[c] - m);
    float lse = m + logf(s);
    if (lane < 7) out[wv * 7 + lane] = uv - lse;
}

extern "C" void kernel_launch(void* const* d_in, const int* in_sizes, int n_in,
                              void* d_out, int out_size, void* d_ws, size_t ws_size,
                              hipStream_t stream) {
    const float* x   = (const float*)d_in[0];
    const int*   eix = (const int*)d_in[1];
    const float* W1l = (const float*)d_in[2];
    const float* b1  = (const float*)d_in[3];
    const float* W1r = (const float*)d_in[4];
    const float* W2l = (const float*)d_in[5];
    const float* b2  = (const float*)d_in[6];
    const float* W2r = (const float*)d_in[7];
    const float* W3l = (const float*)d_in[8];
    const float* b3  = (const float*)d_in[9];
    const float* W3r = (const float*)d_in[10];
    const float* M1w = (const float*)d_in[11];
    const float* M1b = (const float*)d_in[12];
    const float* M2w = (const float*)d_in[13];
    const float* M2b = (const float*)d_in[14];
    float* out = (float*)d_out;

    char* w = (char*)d_ws;
    int*   flag = (int*)w;    w += 256;
    int*   srcI = (int*)w;    w += NE * 4;
    int*   dstI = (int*)w;    w += NE * 4;
    float* deg  = (float*)w;  w += 40960;
    // zero block: agg1 | agg2 | agg3 (one memset)
    float* agg1 = (float*)w;  w += NN * 64 * 4;
    float* agg2 = (float*)w;  w += NN * 32 * 4;
    float* agg3 = (float*)w;  w += NN * 32 * 4;
    float* y    = (float*)w;  w += NN * 128 * 4;
    float* yp   = (float*)w;  w += (size_t)SK1 * NN * 128 * 4;
    float* y2   = (float*)w;  w += NN * 64 * 4;
    float* y3   = (float*)w;  w += NN * 64 * 4;
    u16*   Wb   = (u16*)w;    w += 128 * KP * 2;

    detect_kernel<<<1, 256, 0, stream>>>(eix, flag);
    hipMemsetAsync(deg, 0, NN * 4, stream);
    repackdeg_kernel<<<(NE + 255) / 256, 256, 0, stream>>>(eix, flag, srcI, dstI, deg);
    deginv_kernel<<<(NN + 255) / 256, 256, 0, stream>>>(deg);

    convw_kernel<<<(128 * (KP / 8) + 255) / 256, 256, 0, stream>>>(W1l, W1r, Wb);

    hipMemsetAsync(agg1, 0, (size_t)NN * 128 * 4, stream);  // agg1+agg2+agg3

    // layer 1: global_load_lds staging, no atomics
    {
        dim3 grid((NN + 31) / 32, SK1);
        mm1_mfma<<<grid, 256, 0, stream>>>(x, Wb, yp);
    }
    yreduce_kernel<<<(NN * 128 / 4 + 255) / 256, 256, 0, stream>>>(yp, y);
    agg_kernel<64, 128><<<(NE * 64) / 256, 256, 0, stream>>>(y, srcI, dstI, agg1);

    // layer 2 (combine fused into GEMM staging)
    mm23_fused<64><<<(NN + 31) / 32, 256, 0, stream>>>(agg1, y, deg, b1, W2l, W2r, y2);
    agg_kernel<32, 64><<<(NE * 32) / 256, 256, 0, stream>>>(y2, srcI, dstI, agg2);

    // layer 3
    mm23_fused<32><<<(NN + 31) / 32, 256, 0, stream>>>(agg2, y2, deg, b2, W3l, W3r, y3);
    agg_kernel<32, 64><<<(NE * 32) / 256, 256, 0, stream>>>(y3, srcI, dstI, agg3);

    // combine3 + post_mp + log_softmax
    final_fused<<<(NN + 3) / 4, 256, 0, stream>>>(agg3, y3, deg, b3, M1w, M1b, M2w, M2b, out);
}